// Round 3
// baseline (511.360 us; speedup 1.0000x reference)
//
#include <hip/hip_runtime.h>
#include <stdint.h>

// ---------- types ----------
typedef __attribute__((ext_vector_type(4))) float f32x4;
typedef __attribute__((ext_vector_type(8))) short short8;

#define MFMA_BF16(a, b, c) __builtin_amdgcn_mfma_f32_16x16x32_bf16(a, b, c, 0, 0, 0)

#define GLD16(gp, lp)                                                          \
  __builtin_amdgcn_global_load_lds(                                            \
      (const __attribute__((address_space(1))) void*)(gp),                     \
      (__attribute__((address_space(3))) void*)(lp), 16, 0, 0)

__device__ __forceinline__ short f2bf(float f) {
  union { float f; uint32_t u; } v; v.f = f;
  uint32_t r = (v.u + 0x7FFFu + ((v.u >> 16) & 1u)) >> 16;
  return (short)r;
}
__device__ __forceinline__ float bf2f(short s) {
  union { uint32_t u; float f; } v; v.u = ((uint32_t)(uint16_t)s) << 16;
  return v.f;
}
__device__ __forceinline__ short f2bf_trunc(float f) {
  union { float f; uint32_t u; } v; v.f = f;
  return (short)(v.u >> 16);
}

// ---------- elementwise split / cast ----------
__global__ __launch_bounds__(256) void split_pair(const float* __restrict__ src,
                                                  short* __restrict__ dh,
                                                  short* __restrict__ dl, int n) {
  int i = blockIdx.x * 256 + threadIdx.x;
  if (i < n) {
    float v = src[i];
    short hv = f2bf(v);
    dh[i] = hv;
    dl[i] = f2bf(v - bf2f(hv));
  }
}

__global__ __launch_bounds__(256) void cast_bf16(const float* __restrict__ src,
                                                 short* __restrict__ d, int n) {
  int i = blockIdx.x * 256 + threadIdx.x;
  if (i < n) d[i] = f2bf(src[i]);
}

// ---------- fused QKV projection GEMM ----------
// C[m,n] = sum_k X[m,k] * W[n,k],  M=8192, N=3072 (Q|K|V), K=1024
// 3-term split-bf16. Epilogue: Q/K -> hi/lo [B,H,S,64]; V -> TRANSPOSED [B,H,64,S].
__global__ __launch_bounds__(256) void gemm_proj(
    const short* __restrict__ Xh, const short* __restrict__ Xl,
    const short* __restrict__ Wh, const short* __restrict__ Wl,
    short* __restrict__ Qh, short* __restrict__ Ql,
    short* __restrict__ Kh, short* __restrict__ Kl,
    short* __restrict__ Vt) {
  __shared__ short sAh[128 * 32], sAl[128 * 32], sBh[128 * 32], sBl[128 * 32];
  const int tid = threadIdx.x, lane = tid & 63, w = tid >> 6;
  const int wr = w >> 1, wc = w & 1;
  const int g = lane >> 4, c = lane & 15;
  const int m0 = blockIdx.y * 128, n0 = blockIdx.x * 128;

  f32x4 acc[4][4];
#pragma unroll
  for (int i = 0; i < 4; i++)
#pragma unroll
    for (int j = 0; j < 4; j++) acc[i][j] = (f32x4){0.f, 0.f, 0.f, 0.f};

  for (int ks = 0; ks < 32; ks++) {
    const int k0 = ks * 32;
    __syncthreads();
#pragma unroll
    for (int i = 0; i < 2; i++) {
      const int chunk = i * 256 + w * 64 + lane;
      const int row = chunk >> 2;
      const int col = (chunk & 3) * 8;
      const size_t aoff = (size_t)(m0 + row) * 1024 + k0 + col;
      const size_t boff = (size_t)(n0 + row) * 1024 + k0 + col;
      const int ldsoff = (i * 256 + w * 64) * 16;
      GLD16(Xh + aoff, (char*)sAh + ldsoff);
      GLD16(Xl + aoff, (char*)sAl + ldsoff);
      GLD16(Wh + boff, (char*)sBh + ldsoff);
      GLD16(Wl + boff, (char*)sBl + ldsoff);
    }
    asm volatile("s_waitcnt vmcnt(0)" ::: "memory");
    __syncthreads();

    short8 ah[4], al[4], bh[4], bl[4];
#pragma unroll
    for (int i = 0; i < 4; i++) {
      const int ar = (wr * 64 + i * 16 + c) * 32 + g * 8;
      const int br = (wc * 64 + i * 16 + c) * 32 + g * 8;
      ah[i] = *(const short8*)&sAh[ar];
      al[i] = *(const short8*)&sAl[ar];
      bh[i] = *(const short8*)&sBh[br];
      bl[i] = *(const short8*)&sBl[br];
    }
#pragma unroll
    for (int i = 0; i < 4; i++)
#pragma unroll
      for (int j = 0; j < 4; j++) {
        acc[i][j] = MFMA_BF16(ah[i], bh[j], acc[i][j]);
        acc[i][j] = MFMA_BF16(ah[i], bl[j], acc[i][j]);
        acc[i][j] = MFMA_BF16(al[i], bh[j], acc[i][j]);
      }
  }

  const int section = n0 >> 10;  // 0=Q 1=K 2=V
#pragma unroll
  for (int i = 0; i < 4; i++)
#pragma unroll
    for (int j = 0; j < 4; j++)
#pragma unroll
      for (int r = 0; r < 4; r++) {
        const float v = acc[i][j][r];
        const int m = m0 + wr * 64 + i * 16 + g * 4 + r;
        const int n = n0 + wc * 64 + j * 16 + c;
        const int b = m >> 11, s = m & 2047;
        const int nn = n & 1023;
        const int hh = nn >> 6, d = nn & 63;
        if (section == 0) {
          const size_t off = ((size_t)(b * 16 + hh) * 2048 + s) * 64 + d;
          short hv = f2bf(v);
          Qh[off] = hv;
          Ql[off] = f2bf(v - bf2f(hv));
        } else if (section == 1) {
          const size_t off = ((size_t)(b * 16 + hh) * 2048 + s) * 64 + d;
          short hv = f2bf(v);
          Kh[off] = hv;
          Kl[off] = f2bf(v - bf2f(hv));
        } else {
          // transposed: Vt[(bh*64 + d)*2048 + s]
          Vt[((size_t)(b * 16 + hh) * 64 + d) * 2048 + s] = f2bf(v);
        }
      }
}

// ---------- flash attention ----------
// grid 1024 (XCD-chunk-swizzled -> 16 qblocks x 64 bh). block = 512 (8 waves x 16 q-rows).
// KV tiles double-buffered (2-phase pipeline): stage t+1 while computing t,
// one vmcnt(0)+barrier per tile. LDS tiles XOR-swizzled (chunk ^= row&7);
// global_load_lds dest linear, GLOBAL source pre-swizzled.
__global__ __launch_bounds__(512) void attn_kernel(
    const short* __restrict__ Qh, const short* __restrict__ Ql,
    const short* __restrict__ Kh, const short* __restrict__ Kl,
    const short* __restrict__ Vt, short* __restrict__ Z) {
  __shared__ short sKh[2][64 * 64], sKl[2][64 * 64], sV[2][64 * 64];
  __shared__ short sP[8][16 * 64];
  const int tid = threadIdx.x, lane = tid & 63, w = tid >> 6;
  const int g = lane >> 4, c = lane & 15;
  // XCD chunk swizzle: 1024 blocks, consecutive hw ids round-robin XCDs;
  // give each XCD a contiguous 128-block range (8 bh's worth).
  const int L = blockIdx.x;
  const int wid = (L & 7) * 128 + (L >> 3);
  const int qblk = wid & 15, bh = wid >> 4;
  const int b = bh >> 4, h = bh & 15;
  const size_t base = (size_t)bh * (2048 * 64);

  // Q fragments (held for whole kernel)
  short8 qh[2], ql[2];
  {
    const int qrow = qblk * 128 + w * 16 + c;
#pragma unroll
    for (int cc = 0; cc < 2; cc++) {
      const size_t off = base + (size_t)qrow * 64 + cc * 32 + g * 8;
      qh[cc] = *(const short8*)(Qh + off);
      ql[cc] = *(const short8*)(Ql + off);
    }
  }

  f32x4 zacc[4];
  float m_run[4], l_run[4];
#pragma unroll
  for (int dt = 0; dt < 4; dt++) zacc[dt] = (f32x4){0.f, 0.f, 0.f, 0.f};
#pragma unroll
  for (int r = 0; r < 4; r++) { m_run[r] = -INFINITY; l_run[r] = 0.f; }

  // per-thread swizzled chunk indices for fragment reads
  const int sw0 = ((0 * 4 + g) ^ (c & 7)) * 8;
  const int sw1 = ((1 * 4 + g) ^ (c & 7)) * 8;

  // staging geometry: one 16B chunk per array per thread (512 thr x 16B = 8KB tile)
  const int chunk = tid;             // 0..511
  const int srow = chunk >> 3;       // 0..63
  const int scolg = (chunk & 7) ^ (srow & 7);  // pre-swizzled global chunk
  const int sldsoff = chunk * 16;
  const size_t gK0 = base + (size_t)srow * 64 + scolg * 8;    // + kt*4096
  const size_t gV0 = base + (size_t)srow * 2048 + scolg * 8;  // + kt*64

  auto stage = [&](int buf, int kt) {
    GLD16(Kh + gK0 + (size_t)kt * 4096, (char*)&sKh[buf][0] + sldsoff);
    GLD16(Kl + gK0 + (size_t)kt * 4096, (char*)&sKl[buf][0] + sldsoff);
    GLD16(Vt + gV0 + (size_t)kt * 64,   (char*)&sV[buf][0] + sldsoff);
  };

  auto compute = [&](int buf) {
    // QK^T (3-term split) -> 16x64 scores per wave
    f32x4 sacc[4];
#pragma unroll
    for (int t = 0; t < 4; t++) sacc[t] = (f32x4){0.f, 0.f, 0.f, 0.f};
    __builtin_amdgcn_s_setprio(1);
#pragma unroll
    for (int cc = 0; cc < 2; cc++) {
      const int sw = cc ? sw1 : sw0;
#pragma unroll
      for (int t = 0; t < 4; t++) {
        const int kr = (t * 16 + c) * 64 + sw;
        short8 kh8 = *(const short8*)&sKh[buf][kr];
        short8 kl8 = *(const short8*)&sKl[buf][kr];
        sacc[t] = MFMA_BF16(qh[cc], kh8, sacc[t]);
        sacc[t] = MFMA_BF16(qh[cc], kl8, sacc[t]);
        sacc[t] = MFMA_BF16(ql[cc], kh8, sacc[t]);
      }
    }
    __builtin_amdgcn_s_setprio(0);

    // mask, scale, online softmax
    float lg[4][4];  // [t][r]
    float tmax[4];
#pragma unroll
    for (int r = 0; r < 4; r++) tmax[r] = -INFINITY;
#pragma unroll
    for (int t = 0; t < 4; t++)
#pragma unroll
      for (int r = 0; r < 4; r++) {
        float s = sacc[t][r];
        if (s == 0.0f) s = -1e9f;   // reference's zero-value mask
        s *= 8.0f;                  // * sqrt(d_k)
        lg[t][r] = s;
        tmax[r] = fmaxf(tmax[r], s);
      }
#pragma unroll
    for (int r = 0; r < 4; r++) {
#pragma unroll
      for (int off = 8; off >= 1; off >>= 1)
        tmax[r] = fmaxf(tmax[r], __shfl_xor(tmax[r], off, 16));
    }
    float scale[4], rsum[4];
#pragma unroll
    for (int r = 0; r < 4; r++) {
      const float mnew = fmaxf(m_run[r], tmax[r]);
      scale[r] = __expf(m_run[r] - mnew);
      m_run[r] = mnew;
      float rs = 0.f;
#pragma unroll
      for (int t = 0; t < 4; t++) {
        lg[t][r] = __expf(lg[t][r] - mnew);
        rs += lg[t][r];
      }
      rsum[r] = rs;
    }
#pragma unroll
    for (int r = 0; r < 4; r++) {
#pragma unroll
      for (int off = 8; off >= 1; off >>= 1)
        rsum[r] += __shfl_xor(rsum[r], off, 16);
      l_run[r] = l_run[r] * scale[r] + rsum[r];
    }
#pragma unroll
    for (int dt = 0; dt < 4; dt++)
#pragma unroll
      for (int r = 0; r < 4; r++) zacc[dt][r] *= scale[r];

    // write P (bf16, truncated) to per-wave LDS, swizzled
#pragma unroll
    for (int t = 0; t < 4; t++)
#pragma unroll
      for (int r = 0; r < 4; r++) {
        const int row = g * 4 + r;
        const int col = t * 16 + c;
        sP[w][row * 64 + (((col >> 3) ^ (row & 7)) * 8) + (col & 7)] =
            f2bf_trunc(lg[t][r]);
      }
    asm volatile("s_waitcnt lgkmcnt(0)" ::: "memory");

    // PV: A = P row c, B = Vt row dt*16+c (k contiguous)
    __builtin_amdgcn_s_setprio(1);
#pragma unroll
    for (int cc = 0; cc < 2; cc++) {
      const int sw = cc ? sw1 : sw0;
      short8 pa = *(const short8*)&sP[w][c * 64 + sw];
#pragma unroll
      for (int dt = 0; dt < 4; dt++) {
        short8 vb = *(const short8*)&sV[buf][(dt * 16 + c) * 64 + sw];
        zacc[dt] = MFMA_BF16(pa, vb, zacc[dt]);
      }
    }
    __builtin_amdgcn_s_setprio(0);
  };

  // prologue
  stage(0, 0);
  asm volatile("s_waitcnt vmcnt(0)" ::: "memory");
  __builtin_amdgcn_s_barrier();

#pragma unroll 1
  for (int t2 = 0; t2 < 16; t2++) {
    {
      const int t = t2 * 2;
      stage(1, t + 1);          // prefetch next tile into buf1
      compute(0);               // compute current from buf0
      asm volatile("s_waitcnt vmcnt(0) lgkmcnt(0)" ::: "memory");
      __builtin_amdgcn_s_barrier();
    }
    {
      const int t = t2 * 2 + 1;
      stage(0, t + 1 < 32 ? t + 1 : 31);  // clamp (last restages 31, unused)
      compute(1);
      asm volatile("s_waitcnt vmcnt(0) lgkmcnt(0)" ::: "memory");
      __builtin_amdgcn_s_barrier();
    }
  }

  // epilogue: normalize, store Z[b*2048+q][h*64+d] bf16
  float inv[4];
#pragma unroll
  for (int r = 0; r < 4; r++) inv[r] = l_run[r] > 0.f ? 1.0f / l_run[r] : 0.f;
#pragma unroll
  for (int dt = 0; dt < 4; dt++)
#pragma unroll
    for (int r = 0; r < 4; r++) {
      const int qg = qblk * 128 + w * 16 + g * 4 + r;
      const int col = h * 64 + dt * 16 + c;
      Z[(size_t)(b * 2048 + qg) * 1024 + col] = f2bf(zacc[dt][r] * inv[r]);
    }
}

// ---------- output projection GEMM ----------
// out[m,n] = sum_k Z[m,k]*Wo[n,k] + bo[n], M=8192, N=1024, K=1024, fp32 out
__global__ __launch_bounds__(256) void gemm_out(
    const short* __restrict__ Zb, const short* __restrict__ Wob,
    const float* __restrict__ bo, float* __restrict__ out) {
  __shared__ short sA[128 * 32], sB[128 * 32];
  const int tid = threadIdx.x, lane = tid & 63, w = tid >> 6;
  const int wr = w >> 1, wc = w & 1;
  const int g = lane >> 4, c = lane & 15;
  const int m0 = blockIdx.y * 128, n0 = blockIdx.x * 128;

  f32x4 acc[4][4];
#pragma unroll
  for (int i = 0; i < 4; i++)
#pragma unroll
    for (int j = 0; j < 4; j++) acc[i][j] = (f32x4){0.f, 0.f, 0.f, 0.f};

  for (int ks = 0; ks < 32; ks++) {
    const int k0 = ks * 32;
    __syncthreads();
#pragma unroll
    for (int i = 0; i < 2; i++) {
      const int chunk = i * 256 + w * 64 + lane;
      const int row = chunk >> 2;
      const int col = (chunk & 3) * 8;
      const size_t aoff = (size_t)(m0 + row) * 1024 + k0 + col;
      const size_t boff = (size_t)(n0 + row) * 1024 + k0 + col;
      const int ldsoff = (i * 256 + w * 64) * 16;
      GLD16(Zb + aoff, (char*)sA + ldsoff);
      GLD16(Wob + boff, (char*)sB + ldsoff);
    }
    asm volatile("s_waitcnt vmcnt(0)" ::: "memory");
    __syncthreads();

    short8 a[4], b8[4];
#pragma unroll
    for (int i = 0; i < 4; i++) {
      a[i] = *(const short8*)&sA[(wr * 64 + i * 16 + c) * 32 + g * 8];
      b8[i] = *(const short8*)&sB[(wc * 64 + i * 16 + c) * 32 + g * 8];
    }
#pragma unroll
    for (int i = 0; i < 4; i++)
#pragma unroll
      for (int j = 0; j < 4; j++) acc[i][j] = MFMA_BF16(a[i], b8[j], acc[i][j]);
  }

#pragma unroll
  for (int i = 0; i < 4; i++)
#pragma unroll
    for (int j = 0; j < 4; j++)
#pragma unroll
      for (int r = 0; r < 4; r++) {
        const int m = m0 + wr * 64 + i * 16 + g * 4 + r;
        const int n = n0 + wc * 64 + j * 16 + c;
        out[(size_t)m * 1024 + n] = acc[i][j][r] + bo[n];
      }
}

// ---------- host ----------
extern "C" void kernel_launch(void* const* d_in, const int* in_sizes, int n_in,
                              void* d_out, int out_size, void* d_ws, size_t ws_size,
                              hipStream_t stream) {
  const float* x  = (const float*)d_in[0];
  const float* Wq = (const float*)d_in[1];
  const float* Wk = (const float*)d_in[2];
  const float* Wv = (const float*)d_in[3];
  const float* Wo = (const float*)d_in[4];
  const float* bo = (const float*)d_in[5];
  float* out = (float*)d_out;

  const size_t NX = 8388608;   // B*S*D_MODEL
  const size_t NW = 1048576;   // per-projection weight elements
  const size_t NQ = 8388608;   // B*H*S*D_K

  char* p = (char*)d_ws;
  auto take = [&](size_t bytes) -> char* {
    char* r = p;
    p += (bytes + 255) & ~(size_t)255;
    return r;
  };
  short* xh  = (short*)take(NX * 2);
  short* xl  = (short*)take(NX * 2);
  short* Wh  = (short*)take(3 * NW * 2);
  short* Wl  = (short*)take(3 * NW * 2);
  short* Woh = (short*)take(NW * 2);
  short* Qh  = (short*)take(NQ * 2);
  short* Ql  = (short*)take(NQ * 2);
  short* Kh  = (short*)take(NQ * 2);
  short* Kl  = (short*)take(NQ * 2);
  short* Vt  = (short*)take(NQ * 2);
  short* Zb  = (short*)take(NQ * 2);

  split_pair<<<dim3((int)(NX / 256)), 256, 0, stream>>>(x, xh, xl, (int)NX);
  split_pair<<<dim3((int)(NW / 256)), 256, 0, stream>>>(Wq, Wh, Wl, (int)NW);
  split_pair<<<dim3((int)(NW / 256)), 256, 0, stream>>>(Wk, Wh + NW, Wl + NW, (int)NW);
  split_pair<<<dim3((int)(NW / 256)), 256, 0, stream>>>(Wv, Wh + 2 * NW, Wl + 2 * NW, (int)NW);
  cast_bf16<<<dim3((int)(NW / 256)), 256, 0, stream>>>(Wo, Woh, (int)NW);

  gemm_proj<<<dim3(24, 64), 256, 0, stream>>>(xh, xl, Wh, Wl, Qh, Ql, Kh, Kl, Vt);
  attn_kernel<<<dim3(1024), 512, 0, stream>>>(Qh, Ql, Kh, Kl, Vt, Zb);
  gemm_out<<<dim3(8, 64), 256, 0, stream>>>(Zb, Woh, bo, out);
}

// Round 4
// 475.783 us; speedup vs baseline: 1.0748x; 1.0748x over previous
//
#include <hip/hip_runtime.h>
#include <stdint.h>

// ---------- types ----------
typedef __attribute__((ext_vector_type(4))) float f32x4;
typedef __attribute__((ext_vector_type(8))) short short8;

#define MFMA_BF16(a, b, c) __builtin_amdgcn_mfma_f32_16x16x32_bf16(a, b, c, 0, 0, 0)

#define GLD16(gp, lp)                                                          \
  __builtin_amdgcn_global_load_lds(                                            \
      (const __attribute__((address_space(1))) void*)(gp),                     \
      (__attribute__((address_space(3))) void*)(lp), 16, 0, 0)

__device__ __forceinline__ short f2bf(float f) {
  union { float f; uint32_t u; } v; v.f = f;
  uint32_t r = (v.u + 0x7FFFu + ((v.u >> 16) & 1u)) >> 16;
  return (short)r;
}
__device__ __forceinline__ float bf2f(short s) {
  union { uint32_t u; float f; } v; v.u = ((uint32_t)(uint16_t)s) << 16;
  return v.f;
}
__device__ __forceinline__ short f2bf_trunc(float f) {
  union { float f; uint32_t u; } v; v.f = f;
  return (short)(v.u >> 16);
}

// ---------- elementwise split / cast ----------
__global__ __launch_bounds__(256) void split_pair(const float* __restrict__ src,
                                                  short* __restrict__ dh,
                                                  short* __restrict__ dl, int n) {
  int i = blockIdx.x * 256 + threadIdx.x;
  if (i < n) {
    float v = src[i];
    short hv = f2bf(v);
    dh[i] = hv;
    dl[i] = f2bf(v - bf2f(hv));
  }
}

__global__ __launch_bounds__(256) void cast_bf16(const float* __restrict__ src,
                                                 short* __restrict__ d, int n) {
  int i = blockIdx.x * 256 + threadIdx.x;
  if (i < n) d[i] = f2bf(src[i]);
}

// ---------- fused QKV projection GEMM ----------
// C[m,n] = sum_k X[m,k] * W[n,k],  M=8192, N=3072 (Q|K|V), K=1024
// 3-term split-bf16. Epilogue: Q/K -> hi/lo [B,H,S,64]; V -> TRANSPOSED [B,H,64,S].
__global__ __launch_bounds__(256) void gemm_proj(
    const short* __restrict__ Xh, const short* __restrict__ Xl,
    const short* __restrict__ Wh, const short* __restrict__ Wl,
    short* __restrict__ Qh, short* __restrict__ Ql,
    short* __restrict__ Kh, short* __restrict__ Kl,
    short* __restrict__ Vt) {
  __shared__ short sAh[128 * 32], sAl[128 * 32], sBh[128 * 32], sBl[128 * 32];
  const int tid = threadIdx.x, lane = tid & 63, w = tid >> 6;
  const int wr = w >> 1, wc = w & 1;
  const int g = lane >> 4, c = lane & 15;
  const int m0 = blockIdx.y * 128, n0 = blockIdx.x * 128;

  f32x4 acc[4][4];
#pragma unroll
  for (int i = 0; i < 4; i++)
#pragma unroll
    for (int j = 0; j < 4; j++) acc[i][j] = (f32x4){0.f, 0.f, 0.f, 0.f};

  for (int ks = 0; ks < 32; ks++) {
    const int k0 = ks * 32;
    __syncthreads();
#pragma unroll
    for (int i = 0; i < 2; i++) {
      const int chunk = i * 256 + w * 64 + lane;
      const int row = chunk >> 2;
      const int col = (chunk & 3) * 8;
      const size_t aoff = (size_t)(m0 + row) * 1024 + k0 + col;
      const size_t boff = (size_t)(n0 + row) * 1024 + k0 + col;
      const int ldsoff = (i * 256 + w * 64) * 16;
      GLD16(Xh + aoff, (char*)sAh + ldsoff);
      GLD16(Xl + aoff, (char*)sAl + ldsoff);
      GLD16(Wh + boff, (char*)sBh + ldsoff);
      GLD16(Wl + boff, (char*)sBl + ldsoff);
    }
    asm volatile("s_waitcnt vmcnt(0)" ::: "memory");
    __syncthreads();

    short8 ah[4], al[4], bh[4], bl[4];
#pragma unroll
    for (int i = 0; i < 4; i++) {
      const int ar = (wr * 64 + i * 16 + c) * 32 + g * 8;
      const int br = (wc * 64 + i * 16 + c) * 32 + g * 8;
      ah[i] = *(const short8*)&sAh[ar];
      al[i] = *(const short8*)&sAl[ar];
      bh[i] = *(const short8*)&sBh[br];
      bl[i] = *(const short8*)&sBl[br];
    }
#pragma unroll
    for (int i = 0; i < 4; i++)
#pragma unroll
      for (int j = 0; j < 4; j++) {
        acc[i][j] = MFMA_BF16(ah[i], bh[j], acc[i][j]);
        acc[i][j] = MFMA_BF16(ah[i], bl[j], acc[i][j]);
        acc[i][j] = MFMA_BF16(al[i], bh[j], acc[i][j]);
      }
  }

  const int section = n0 >> 10;  // 0=Q 1=K 2=V
#pragma unroll
  for (int i = 0; i < 4; i++)
#pragma unroll
    for (int j = 0; j < 4; j++)
#pragma unroll
      for (int r = 0; r < 4; r++) {
        const float v = acc[i][j][r];
        const int m = m0 + wr * 64 + i * 16 + g * 4 + r;
        const int n = n0 + wc * 64 + j * 16 + c;
        const int b = m >> 11, s = m & 2047;
        const int nn = n & 1023;
        const int hh = nn >> 6, d = nn & 63;
        if (section == 0) {
          const size_t off = ((size_t)(b * 16 + hh) * 2048 + s) * 64 + d;
          short hv = f2bf(v);
          Qh[off] = hv;
          Ql[off] = f2bf(v - bf2f(hv));
        } else if (section == 1) {
          const size_t off = ((size_t)(b * 16 + hh) * 2048 + s) * 64 + d;
          short hv = f2bf(v);
          Kh[off] = hv;
          Kl[off] = f2bf(v - bf2f(hv));
        } else {
          // transposed: Vt[(bh*64 + d)*2048 + s]
          Vt[((size_t)(b * 16 + hh) * 64 + d) * 2048 + s] = f2bf(v);
        }
      }
}

// ---------- flash attention ----------
// grid 2048 (XCD-chunked: 8 chunks of 256 = 8 bh x 32 qblk each).
// block = 256 (4 waves x 16 q-rows). KVBLK = 32, double-buffered 2-phase
// pipeline: stage t+1 while computing t, one vmcnt(0)+barrier per tile.
// LDS = 28KB -> 5 blocks/CU. All tiles XOR-swizzled in 16B chunks
// (mask depends on row; global source pre-swizzled, LDS dest linear).
__global__ __launch_bounds__(256) void attn_kernel(
    const short* __restrict__ Qh, const short* __restrict__ Ql,
    const short* __restrict__ Kh, const short* __restrict__ Kl,
    const short* __restrict__ Vt, short* __restrict__ Z) {
  __shared__ short sKh[2][32 * 64], sKl[2][32 * 64];  // [k-row][d]
  __shared__ short sV[2][64 * 32];                    // [d-row][s]
  __shared__ short sP[4][16 * 32];                    // per-wave [q-row][k]
  const int tid = threadIdx.x, lane = tid & 63, w = tid >> 6;
  const int g = lane >> 4, c = lane & 15;
  // XCD chunk swizzle: each XCD gets 256 consecutive work-ids (8 bh).
  const int L = blockIdx.x;
  const int wid = (L & 7) * 256 + (L >> 3);
  const int qblk = wid & 31, bh = wid >> 5;
  const int b = bh >> 4, h = bh & 15;
  const size_t base = (size_t)bh * (2048 * 64);

  // Q fragments (held for whole kernel)
  short8 qh[2], ql[2];
  {
    const int qrow = qblk * 64 + w * 16 + c;
#pragma unroll
    for (int cc = 0; cc < 2; cc++) {
      const size_t off = base + (size_t)qrow * 64 + cc * 32 + g * 8;
      qh[cc] = *(const short8*)(Qh + off);
      ql[cc] = *(const short8*)(Ql + off);
    }
  }

  f32x4 zacc[4];
  float m_run[4], l_part[4];
#pragma unroll
  for (int dt = 0; dt < 4; dt++) zacc[dt] = (f32x4){0.f, 0.f, 0.f, 0.f};
#pragma unroll
  for (int r = 0; r < 4; r++) { m_run[r] = -INFINITY; l_part[r] = 0.f; }

  // fragment-read swizzled chunk offsets
  const int swK0 = ((0 * 4 + g) ^ (c & 7)) * 8;             // K d-chunks (8/row)
  const int swK1 = ((1 * 4 + g) ^ (c & 7)) * 8;
  const int m4c = (c ^ (c >> 2)) & 3;                        // 4-chunk mask(row=c)
  const int swPV = (g ^ m4c) * 8;                            // P/V s-chunks (4/row)

  // staging geometry (256 threads, 1 chunk of 16B per array per thread)
  // K: 32 rows x 8 chunks; V: 64 rows x 4 chunks
  const int krow = tid >> 3, kcolg = (tid & 7) ^ (krow & 7);
  const int vrow = tid >> 2, vcolg = (tid & 3) ^ ((vrow ^ (vrow >> 2)) & 3);
  const int sldsoff = tid * 16;
  const size_t gK0 = base + (size_t)krow * 64 + kcolg * 8;    // + kt*2048
  const size_t gV0 = base + (size_t)vrow * 2048 + vcolg * 8;  // + kt*32

  auto stage = [&](int buf, int kt) {
    GLD16(Kh + gK0 + (size_t)kt * 2048, (char*)&sKh[buf][0] + sldsoff);
    GLD16(Kl + gK0 + (size_t)kt * 2048, (char*)&sKl[buf][0] + sldsoff);
    GLD16(Vt + gV0 + (size_t)kt * 32,   (char*)&sV[buf][0] + sldsoff);
  };

  auto compute = [&](int buf) {
    // QK^T (3-term split) -> 16q x 32k scores per wave
    f32x4 sacc[2];
#pragma unroll
    for (int t = 0; t < 2; t++) sacc[t] = (f32x4){0.f, 0.f, 0.f, 0.f};
    __builtin_amdgcn_s_setprio(1);
#pragma unroll
    for (int cc = 0; cc < 2; cc++) {
      const int sw = cc ? swK1 : swK0;
#pragma unroll
      for (int t = 0; t < 2; t++) {
        const int kr = (t * 16 + c) * 64 + sw;
        short8 kh8 = *(const short8*)&sKh[buf][kr];
        short8 kl8 = *(const short8*)&sKl[buf][kr];
        sacc[t] = MFMA_BF16(qh[cc], kh8, sacc[t]);
        sacc[t] = MFMA_BF16(qh[cc], kl8, sacc[t]);
        sacc[t] = MFMA_BF16(ql[cc], kh8, sacc[t]);
      }
    }
    __builtin_amdgcn_s_setprio(0);

    // mask, scale, online softmax (sum deferred to epilogue)
    float lg[2][4];
    float tmax[4];
#pragma unroll
    for (int t = 0; t < 2; t++)
#pragma unroll
      for (int r = 0; r < 4; r++) {
        float s = sacc[t][r];
        if (s == 0.0f) s = -1e9f;   // reference's zero-value mask
        s *= 8.0f;                  // * sqrt(d_k)
        lg[t][r] = s;
      }
#pragma unroll
    for (int r = 0; r < 4; r++) {
      tmax[r] = fmaxf(lg[0][r], lg[1][r]);
#pragma unroll
      for (int off = 8; off >= 1; off >>= 1)
        tmax[r] = fmaxf(tmax[r], __shfl_xor(tmax[r], off, 16));
    }
#pragma unroll
    for (int r = 0; r < 4; r++) {
      const float mnew = fmaxf(m_run[r], tmax[r]);
      const float scale = __expf(m_run[r] - mnew);
      m_run[r] = mnew;
      lg[0][r] = __expf(lg[0][r] - mnew);
      lg[1][r] = __expf(lg[1][r] - mnew);
      l_part[r] = l_part[r] * scale + lg[0][r] + lg[1][r];
#pragma unroll
      for (int dt = 0; dt < 4; dt++) zacc[dt][r] *= scale;
    }

    // write P (bf16, truncated) to per-wave LDS, swizzled (4 chunks/row)
#pragma unroll
    for (int t = 0; t < 2; t++)
#pragma unroll
      for (int r = 0; r < 4; r++) {
        const int row = g * 4 + r;
        const int col = t * 16 + c;
        const int ch = ((col >> 3) ^ ((row ^ (row >> 2)) & 3)) * 8;
        sP[w][row * 32 + ch + (col & 7)] = f2bf_trunc(lg[t][r]);
      }
    asm volatile("s_waitcnt lgkmcnt(0)" ::: "memory");

    // PV: A = P row c (k=g*8+j over 32), B = Vt row dt*16+c (k contiguous)
    __builtin_amdgcn_s_setprio(1);
    short8 pa = *(const short8*)&sP[w][c * 32 + swPV];
#pragma unroll
    for (int dt = 0; dt < 4; dt++) {
      short8 vb = *(const short8*)&sV[buf][(dt * 16 + c) * 32 + swPV];
      zacc[dt] = MFMA_BF16(pa, vb, zacc[dt]);
    }
    __builtin_amdgcn_s_setprio(0);
  };

  // prologue
  stage(0, 0);
  asm volatile("s_waitcnt vmcnt(0)" ::: "memory");
  __builtin_amdgcn_s_barrier();

#pragma unroll 1
  for (int t2 = 0; t2 < 32; t2++) {
    {
      stage(1, 2 * t2 + 1);     // prefetch next tile into buf1
      compute(0);               // compute current from buf0
      asm volatile("s_waitcnt vmcnt(0) lgkmcnt(0)" ::: "memory");
      __builtin_amdgcn_s_barrier();
    }
    {
      const int nxt = 2 * t2 + 2;
      stage(0, nxt < 64 ? nxt : 63);  // clamp (last restages 63, unused)
      compute(1);
      asm volatile("s_waitcnt vmcnt(0) lgkmcnt(0)" ::: "memory");
      __builtin_amdgcn_s_barrier();
    }
  }

  // epilogue: reduce row sums across 16 lanes, normalize, store Z bf16
  float inv[4];
#pragma unroll
  for (int r = 0; r < 4; r++) {
    float rs = l_part[r];
#pragma unroll
    for (int off = 8; off >= 1; off >>= 1) rs += __shfl_xor(rs, off, 16);
    inv[r] = rs > 0.f ? 1.0f / rs : 0.f;
  }
#pragma unroll
  for (int dt = 0; dt < 4; dt++)
#pragma unroll
    for (int r = 0; r < 4; r++) {
      const int qg = qblk * 64 + w * 16 + g * 4 + r;
      const int col = h * 64 + dt * 16 + c;
      Z[(size_t)(b * 2048 + qg) * 1024 + col] = f2bf(zacc[dt][r] * inv[r]);
    }
}

// ---------- output projection GEMM ----------
// out[m,n] = sum_k Z[m,k]*Wo[n,k] + bo[n], M=8192, N=1024, K=1024, fp32 out
__global__ __launch_bounds__(256) void gemm_out(
    const short* __restrict__ Zb, const short* __restrict__ Wob,
    const float* __restrict__ bo, float* __restrict__ out) {
  __shared__ short sA[128 * 32], sB[128 * 32];
  const int tid = threadIdx.x, lane = tid & 63, w = tid >> 6;
  const int wr = w >> 1, wc = w & 1;
  const int g = lane >> 4, c = lane & 15;
  const int m0 = blockIdx.y * 128, n0 = blockIdx.x * 128;

  f32x4 acc[4][4];
#pragma unroll
  for (int i = 0; i < 4; i++)
#pragma unroll
    for (int j = 0; j < 4; j++) acc[i][j] = (f32x4){0.f, 0.f, 0.f, 0.f};

  for (int ks = 0; ks < 32; ks++) {
    const int k0 = ks * 32;
    __syncthreads();
#pragma unroll
    for (int i = 0; i < 2; i++) {
      const int chunk = i * 256 + w * 64 + lane;
      const int row = chunk >> 2;
      const int col = (chunk & 3) * 8;
      const size_t aoff = (size_t)(m0 + row) * 1024 + k0 + col;
      const size_t boff = (size_t)(n0 + row) * 1024 + k0 + col;
      const int ldsoff = (i * 256 + w * 64) * 16;
      GLD16(Zb + aoff, (char*)sA + ldsoff);
      GLD16(Wob + boff, (char*)sB + ldsoff);
    }
    asm volatile("s_waitcnt vmcnt(0)" ::: "memory");
    __syncthreads();

    short8 a[4], b8[4];
#pragma unroll
    for (int i = 0; i < 4; i++) {
      a[i] = *(const short8*)&sA[(wr * 64 + i * 16 + c) * 32 + g * 8];
      b8[i] = *(const short8*)&sB[(wc * 64 + i * 16 + c) * 32 + g * 8];
    }
#pragma unroll
    for (int i = 0; i < 4; i++)
#pragma unroll
      for (int j = 0; j < 4; j++) acc[i][j] = MFMA_BF16(a[i], b8[j], acc[i][j]);
  }

#pragma unroll
  for (int i = 0; i < 4; i++)
#pragma unroll
    for (int j = 0; j < 4; j++)
#pragma unroll
      for (int r = 0; r < 4; r++) {
        const int m = m0 + wr * 64 + i * 16 + g * 4 + r;
        const int n = n0 + wc * 64 + j * 16 + c;
        out[(size_t)m * 1024 + n] = acc[i][j][r] + bo[n];
      }
}

// ---------- host ----------
extern "C" void kernel_launch(void* const* d_in, const int* in_sizes, int n_in,
                              void* d_out, int out_size, void* d_ws, size_t ws_size,
                              hipStream_t stream) {
  const float* x  = (const float*)d_in[0];
  const float* Wq = (const float*)d_in[1];
  const float* Wk = (const float*)d_in[2];
  const float* Wv = (const float*)d_in[3];
  const float* Wo = (const float*)d_in[4];
  const float* bo = (const float*)d_in[5];
  float* out = (float*)d_out;

  const size_t NX = 8388608;   // B*S*D_MODEL
  const size_t NW = 1048576;   // per-projection weight elements
  const size_t NQ = 8388608;   // B*H*S*D_K

  char* p = (char*)d_ws;
  auto take = [&](size_t bytes) -> char* {
    char* r = p;
    p += (bytes + 255) & ~(size_t)255;
    return r;
  };
  short* xh  = (short*)take(NX * 2);
  short* xl  = (short*)take(NX * 2);
  short* Wh  = (short*)take(3 * NW * 2);
  short* Wl  = (short*)take(3 * NW * 2);
  short* Woh = (short*)take(NW * 2);
  short* Qh  = (short*)take(NQ * 2);
  short* Ql  = (short*)take(NQ * 2);
  short* Kh  = (short*)take(NQ * 2);
  short* Kl  = (short*)take(NQ * 2);
  short* Vt  = (short*)take(NQ * 2);
  short* Zb  = (short*)take(NQ * 2);

  split_pair<<<dim3((int)(NX / 256)), 256, 0, stream>>>(x, xh, xl, (int)NX);
  split_pair<<<dim3((int)(NW / 256)), 256, 0, stream>>>(Wq, Wh, Wl, (int)NW);
  split_pair<<<dim3((int)(NW / 256)), 256, 0, stream>>>(Wk, Wh + NW, Wl + NW, (int)NW);
  split_pair<<<dim3((int)(NW / 256)), 256, 0, stream>>>(Wv, Wh + 2 * NW, Wl + 2 * NW, (int)NW);
  cast_bf16<<<dim3((int)(NW / 256)), 256, 0, stream>>>(Wo, Woh, (int)NW);

  gemm_proj<<<dim3(24, 64), 256, 0, stream>>>(xh, xl, Wh, Wl, Qh, Ql, Kh, Kl, Vt);
  attn_kernel<<<dim3(2048), 256, 0, stream>>>(Qh, Ql, Kh, Kl, Vt, Zb);
  gemm_out<<<dim3(8, 64), 256, 0, stream>>>(Zb, Woh, bo, out);
}

// Round 5
// 462.866 us; speedup vs baseline: 1.1048x; 1.0279x over previous
//
#include <hip/hip_runtime.h>
#include <stdint.h>

// ---------- types ----------
typedef __attribute__((ext_vector_type(4))) float f32x4;
typedef __attribute__((ext_vector_type(8))) short short8;

#define MFMA_BF16(a, b, c) __builtin_amdgcn_mfma_f32_16x16x32_bf16(a, b, c, 0, 0, 0)

#define GLD16(gp, lp)                                                          \
  __builtin_amdgcn_global_load_lds(                                            \
      (const __attribute__((address_space(1))) void*)(gp),                     \
      (__attribute__((address_space(3))) void*)(lp), 16, 0, 0)

__device__ __forceinline__ short f2bf(float f) {
  union { float f; uint32_t u; } v; v.f = f;
  uint32_t r = (v.u + 0x7FFFu + ((v.u >> 16) & 1u)) >> 16;
  return (short)r;
}
__device__ __forceinline__ float bf2f(short s) {
  union { uint32_t u; float f; } v; v.u = ((uint32_t)(uint16_t)s) << 16;
  return v.f;
}
__device__ __forceinline__ short f2bf_trunc(float f) {
  union { float f; uint32_t u; } v; v.f = f;
  return (short)(v.u >> 16);
}
__device__ __forceinline__ float exp2_hw(float x) {
  float r;
  asm("v_exp_f32 %0, %1" : "=v"(r) : "v"(x));
  return r;
}

// ---------- elementwise split / cast ----------
__global__ __launch_bounds__(256) void split_pair(const float* __restrict__ src,
                                                  short* __restrict__ dh,
                                                  short* __restrict__ dl, int n) {
  int i = blockIdx.x * 256 + threadIdx.x;
  if (i < n) {
    float v = src[i];
    short hv = f2bf(v);
    dh[i] = hv;
    dl[i] = f2bf(v - bf2f(hv));
  }
}

__global__ __launch_bounds__(256) void cast_bf16(const float* __restrict__ src,
                                                 short* __restrict__ d, int n) {
  int i = blockIdx.x * 256 + threadIdx.x;
  if (i < n) d[i] = f2bf(src[i]);
}

// ---------- fused QKV projection GEMM ----------
// C[m,n] = sum_k X[m,k] * W[n,k],  M=8192, N=3072 (Q|K|V), K=1024
// 3-term split-bf16. Epilogue: Q/K -> hi/lo [B,H,S,64]; V -> TRANSPOSED [B,H,64,S].
__global__ __launch_bounds__(256) void gemm_proj(
    const short* __restrict__ Xh, const short* __restrict__ Xl,
    const short* __restrict__ Wh, const short* __restrict__ Wl,
    short* __restrict__ Qh, short* __restrict__ Ql,
    short* __restrict__ Kh, short* __restrict__ Kl,
    short* __restrict__ Vt) {
  __shared__ short sAh[128 * 32], sAl[128 * 32], sBh[128 * 32], sBl[128 * 32];
  const int tid = threadIdx.x, lane = tid & 63, w = tid >> 6;
  const int wr = w >> 1, wc = w & 1;
  const int g = lane >> 4, c = lane & 15;
  const int m0 = blockIdx.y * 128, n0 = blockIdx.x * 128;

  f32x4 acc[4][4];
#pragma unroll
  for (int i = 0; i < 4; i++)
#pragma unroll
    for (int j = 0; j < 4; j++) acc[i][j] = (f32x4){0.f, 0.f, 0.f, 0.f};

  for (int ks = 0; ks < 32; ks++) {
    const int k0 = ks * 32;
    __syncthreads();
#pragma unroll
    for (int i = 0; i < 2; i++) {
      const int chunk = i * 256 + w * 64 + lane;
      const int row = chunk >> 2;
      const int col = (chunk & 3) * 8;
      const size_t aoff = (size_t)(m0 + row) * 1024 + k0 + col;
      const size_t boff = (size_t)(n0 + row) * 1024 + k0 + col;
      const int ldsoff = (i * 256 + w * 64) * 16;
      GLD16(Xh + aoff, (char*)sAh + ldsoff);
      GLD16(Xl + aoff, (char*)sAl + ldsoff);
      GLD16(Wh + boff, (char*)sBh + ldsoff);
      GLD16(Wl + boff, (char*)sBl + ldsoff);
    }
    asm volatile("s_waitcnt vmcnt(0)" ::: "memory");
    __syncthreads();

    short8 ah[4], al[4], bh[4], bl[4];
#pragma unroll
    for (int i = 0; i < 4; i++) {
      const int ar = (wr * 64 + i * 16 + c) * 32 + g * 8;
      const int br = (wc * 64 + i * 16 + c) * 32 + g * 8;
      ah[i] = *(const short8*)&sAh[ar];
      al[i] = *(const short8*)&sAl[ar];
      bh[i] = *(const short8*)&sBh[br];
      bl[i] = *(const short8*)&sBl[br];
    }
#pragma unroll
    for (int i = 0; i < 4; i++)
#pragma unroll
      for (int j = 0; j < 4; j++) {
        acc[i][j] = MFMA_BF16(ah[i], bh[j], acc[i][j]);
        acc[i][j] = MFMA_BF16(ah[i], bl[j], acc[i][j]);
        acc[i][j] = MFMA_BF16(al[i], bh[j], acc[i][j]);
      }
  }

  const int section = n0 >> 10;  // 0=Q 1=K 2=V
#pragma unroll
  for (int i = 0; i < 4; i++)
#pragma unroll
    for (int j = 0; j < 4; j++)
#pragma unroll
      for (int r = 0; r < 4; r++) {
        const float v = acc[i][j][r];
        const int m = m0 + wr * 64 + i * 16 + g * 4 + r;
        const int n = n0 + wc * 64 + j * 16 + c;
        const int b = m >> 11, s = m & 2047;
        const int nn = n & 1023;
        const int hh = nn >> 6, d = nn & 63;
        if (section == 0) {
          const size_t off = ((size_t)(b * 16 + hh) * 2048 + s) * 64 + d;
          short hv = f2bf(v);
          Qh[off] = hv;
          Ql[off] = f2bf(v - bf2f(hv));
        } else if (section == 1) {
          const size_t off = ((size_t)(b * 16 + hh) * 2048 + s) * 64 + d;
          short hv = f2bf(v);
          Kh[off] = hv;
          Kl[off] = f2bf(v - bf2f(hv));
        } else {
          // transposed: Vt[(bh*64 + d)*2048 + s]
          Vt[((size_t)(b * 16 + hh) * 64 + d) * 2048 + s] = f2bf(v);
        }
      }
}

// ---------- flash attention ----------
// grid 2048 (XCD-chunked: 8 chunks of 256 = 8 bh x 32 qblk each).
// block = 256 (4 waves x 16 q-rows). KVBLK = 32, double-buffered 2-phase
// pipeline. K tiles [32][64] use 3-bit chunk mask (row&7); V/P tiles with
// 64B rows (4 chunks) use mask mu(row) = (row>>1)&3 — per-8-lane-phase
// bijective onto bank groups for read AND <=2-way for P-write.
// Softmax runs in exp2 domain (C = 8*log2e) with defer-max (THR=8).
__global__ __launch_bounds__(256) void attn_kernel(
    const short* __restrict__ Qh, const short* __restrict__ Ql,
    const short* __restrict__ Kh, const short* __restrict__ Kl,
    const short* __restrict__ Vt, short* __restrict__ Z) {
  __shared__ short sKh[2][32 * 64], sKl[2][32 * 64];  // [k-row][d]
  __shared__ short sV[2][64 * 32];                    // [d-row][s]
  __shared__ short sP[4][16 * 32];                    // per-wave [q-row][k]
  const int tid = threadIdx.x, lane = tid & 63, w = tid >> 6;
  const int g = lane >> 4, c = lane & 15;
  // XCD chunk swizzle: each XCD gets 256 consecutive work-ids (8 bh).
  const int L = blockIdx.x;
  const int wid = (L & 7) * 256 + (L >> 3);
  const int qblk = wid & 31, bh = wid >> 5;
  const int b = bh >> 4, h = bh & 15;
  const size_t base = (size_t)bh * (2048 * 64);

  // Q fragments (held for whole kernel)
  short8 qh[2], ql[2];
  {
    const int qrow = qblk * 64 + w * 16 + c;
#pragma unroll
    for (int cc = 0; cc < 2; cc++) {
      const size_t off = base + (size_t)qrow * 64 + cc * 32 + g * 8;
      qh[cc] = *(const short8*)(Qh + off);
      ql[cc] = *(const short8*)(Ql + off);
    }
  }

  f32x4 zacc[4];
  float m_run[4], l_part[4];
#pragma unroll
  for (int dt = 0; dt < 4; dt++) zacc[dt] = (f32x4){0.f, 0.f, 0.f, 0.f};
#pragma unroll
  for (int r = 0; r < 4; r++) { m_run[r] = -INFINITY; l_part[r] = 0.f; }

  // fragment-read swizzled chunk offsets
  const int swK0 = ((0 * 4 + g) ^ (c & 7)) * 8;  // K d-chunks (8/row, 128B rows)
  const int swK1 = ((1 * 4 + g) ^ (c & 7)) * 8;
  const int swPV = (g ^ ((c >> 1) & 3)) * 8;     // V/P s-chunks (4/row, 64B rows)

  // staging geometry (256 threads, 1 chunk of 16B per array per thread)
  // K: 32 rows x 8 chunks (mask row&7); V: 64 rows x 4 chunks (mask (row>>1)&3)
  const int krow = tid >> 3, kcolg = (tid & 7) ^ (krow & 7);
  const int vrow = tid >> 2, vcolg = (tid & 3) ^ ((vrow >> 1) & 3);
  const int sldsoff = tid * 16;
  const size_t gK0 = base + (size_t)krow * 64 + kcolg * 8;    // + kt*2048
  const size_t gV0 = base + (size_t)vrow * 2048 + vcolg * 8;  // + kt*32

  auto stage = [&](int buf, int kt) {
    GLD16(Kh + gK0 + (size_t)kt * 2048, (char*)&sKh[buf][0] + sldsoff);
    GLD16(Kl + gK0 + (size_t)kt * 2048, (char*)&sKl[buf][0] + sldsoff);
    GLD16(Vt + gV0 + (size_t)kt * 32,   (char*)&sV[buf][0] + sldsoff);
  };

  const float CSCL = 11.5415603271f;  // 8 * log2(e): logits in exp2 domain

  auto compute = [&](int buf) {
    // QK^T (3-term split) -> 16q x 32k scores per wave
    f32x4 sacc[2];
#pragma unroll
    for (int t = 0; t < 2; t++) sacc[t] = (f32x4){0.f, 0.f, 0.f, 0.f};
    __builtin_amdgcn_s_setprio(1);
#pragma unroll
    for (int cc = 0; cc < 2; cc++) {
      const int sw = cc ? swK1 : swK0;
#pragma unroll
      for (int t = 0; t < 2; t++) {
        const int kr = (t * 16 + c) * 64 + sw;
        short8 kh8 = *(const short8*)&sKh[buf][kr];
        short8 kl8 = *(const short8*)&sKl[buf][kr];
        sacc[t] = MFMA_BF16(qh[cc], kh8, sacc[t]);
        sacc[t] = MFMA_BF16(qh[cc], kl8, sacc[t]);
        sacc[t] = MFMA_BF16(ql[cc], kh8, sacc[t]);
      }
    }
    __builtin_amdgcn_s_setprio(0);

    // mask + scale into log2 domain
    float lg[2][4];
#pragma unroll
    for (int t = 0; t < 2; t++)
#pragma unroll
      for (int r = 0; r < 4; r++) {
        const float s = sacc[t][r];
        const float v = s * CSCL;
        lg[t][r] = (s == 0.0f) ? -1e10f : v;  // reference's zero-value mask
      }
    // per-row tile max (reduce over 16 lanes)
    float tmax[4];
#pragma unroll
    for (int r = 0; r < 4; r++) {
      tmax[r] = fmaxf(lg[0][r], lg[1][r]);
#pragma unroll
      for (int off = 8; off >= 1; off >>= 1)
        tmax[r] = fmaxf(tmax[r], __shfl_xor(tmax[r], off, 16));
    }
    // defer-max: rescale only when some row grew by > 8 (log2 units)
    const float growmax =
        fmaxf(fmaxf(tmax[0] - m_run[0], tmax[1] - m_run[1]),
              fmaxf(tmax[2] - m_run[2], tmax[3] - m_run[3]));
    if (__any(growmax > 8.0f)) {
#pragma unroll
      for (int r = 0; r < 4; r++) {
        const float mnew = fmaxf(m_run[r], tmax[r]);
        const float sc = exp2_hw(m_run[r] - mnew);
        m_run[r] = mnew;
        l_part[r] *= sc;
#pragma unroll
        for (int dt = 0; dt < 4; dt++) zacc[dt][r] *= sc;
      }
    }
    // P = exp2(lg - m), accumulate row-sums
#pragma unroll
    for (int t = 0; t < 2; t++)
#pragma unroll
      for (int r = 0; r < 4; r++) lg[t][r] = exp2_hw(lg[t][r] - m_run[r]);
#pragma unroll
    for (int r = 0; r < 4; r++) l_part[r] += lg[0][r] + lg[1][r];

    // write P (bf16, truncated) to per-wave LDS, mask mu(row)=(row>>1)&3
#pragma unroll
    for (int t = 0; t < 2; t++)
#pragma unroll
      for (int r = 0; r < 4; r++) {
        const int row = g * 4 + r;
        const int col = t * 16 + c;
        const int ch = ((col >> 3) ^ ((row >> 1) & 3)) * 8;
        sP[w][row * 32 + ch + (col & 7)] = f2bf_trunc(lg[t][r]);
      }
    asm volatile("s_waitcnt lgkmcnt(0)" ::: "memory");

    // PV: A = P row c (k=g*8+j over 32), B = Vt row dt*16+c (k contiguous)
    __builtin_amdgcn_s_setprio(1);
    short8 pa = *(const short8*)&sP[w][c * 32 + swPV];
#pragma unroll
    for (int dt = 0; dt < 4; dt++) {
      short8 vb = *(const short8*)&sV[buf][(dt * 16 + c) * 32 + swPV];
      zacc[dt] = MFMA_BF16(pa, vb, zacc[dt]);
    }
    __builtin_amdgcn_s_setprio(0);
  };

  // prologue
  stage(0, 0);
  asm volatile("s_waitcnt vmcnt(0)" ::: "memory");
  __builtin_amdgcn_s_barrier();

#pragma unroll 1
  for (int t2 = 0; t2 < 32; t2++) {
    {
      stage(1, 2 * t2 + 1);     // prefetch next tile into buf1
      compute(0);               // compute current from buf0
      asm volatile("s_waitcnt vmcnt(0) lgkmcnt(0)" ::: "memory");
      __builtin_amdgcn_s_barrier();
    }
    {
      const int nxt = 2 * t2 + 2;
      stage(0, nxt < 64 ? nxt : 63);  // clamp (last restages 63, unused)
      compute(1);
      asm volatile("s_waitcnt vmcnt(0) lgkmcnt(0)" ::: "memory");
      __builtin_amdgcn_s_barrier();
    }
  }

  // epilogue: reduce row sums across 16 lanes, normalize, store Z bf16
  float inv[4];
#pragma unroll
  for (int r = 0; r < 4; r++) {
    float rs = l_part[r];
#pragma unroll
    for (int off = 8; off >= 1; off >>= 1) rs += __shfl_xor(rs, off, 16);
    inv[r] = rs > 0.f ? 1.0f / rs : 0.f;
  }
#pragma unroll
  for (int dt = 0; dt < 4; dt++)
#pragma unroll
    for (int r = 0; r < 4; r++) {
      const int qg = qblk * 64 + w * 16 + g * 4 + r;
      const int col = h * 64 + dt * 16 + c;
      Z[(size_t)(b * 2048 + qg) * 1024 + col] = f2bf(zacc[dt][r] * inv[r]);
    }
}

// ---------- output projection GEMM ----------
// out[m,n] = sum_k Z[m,k]*Wo[n,k] + bo[n], M=8192, N=1024, K=1024, fp32 out
__global__ __launch_bounds__(256) void gemm_out(
    const short* __restrict__ Zb, const short* __restrict__ Wob,
    const float* __restrict__ bo, float* __restrict__ out) {
  __shared__ short sA[128 * 32], sB[128 * 32];
  const int tid = threadIdx.x, lane = tid & 63, w = tid >> 6;
  const int wr = w >> 1, wc = w & 1;
  const int g = lane >> 4, c = lane & 15;
  const int m0 = blockIdx.y * 128, n0 = blockIdx.x * 128;

  f32x4 acc[4][4];
#pragma unroll
  for (int i = 0; i < 4; i++)
#pragma unroll
    for (int j = 0; j < 4; j++) acc[i][j] = (f32x4){0.f, 0.f, 0.f, 0.f};

  for (int ks = 0; ks < 32; ks++) {
    const int k0 = ks * 32;
    __syncthreads();
#pragma unroll
    for (int i = 0; i < 2; i++) {
      const int chunk = i * 256 + w * 64 + lane;
      const int row = chunk >> 2;
      const int col = (chunk & 3) * 8;
      const size_t aoff = (size_t)(m0 + row) * 1024 + k0 + col;
      const size_t boff = (size_t)(n0 + row) * 1024 + k0 + col;
      const int ldsoff = (i * 256 + w * 64) * 16;
      GLD16(Zb + aoff, (char*)sA + ldsoff);
      GLD16(Wob + boff, (char*)sB + ldsoff);
    }
    asm volatile("s_waitcnt vmcnt(0)" ::: "memory");
    __syncthreads();

    short8 a[4], b8[4];
#pragma unroll
    for (int i = 0; i < 4; i++) {
      a[i] = *(const short8*)&sA[(wr * 64 + i * 16 + c) * 32 + g * 8];
      b8[i] = *(const short8*)&sB[(wc * 64 + i * 16 + c) * 32 + g * 8];
    }
#pragma unroll
    for (int i = 0; i < 4; i++)
#pragma unroll
      for (int j = 0; j < 4; j++) acc[i][j] = MFMA_BF16(a[i], b8[j], acc[i][j]);
  }

#pragma unroll
  for (int i = 0; i < 4; i++)
#pragma unroll
    for (int j = 0; j < 4; j++)
#pragma unroll
      for (int r = 0; r < 4; r++) {
        const int m = m0 + wr * 64 + i * 16 + g * 4 + r;
        const int n = n0 + wc * 64 + j * 16 + c;
        out[(size_t)m * 1024 + n] = acc[i][j][r] + bo[n];
      }
}

// ---------- host ----------
extern "C" void kernel_launch(void* const* d_in, const int* in_sizes, int n_in,
                              void* d_out, int out_size, void* d_ws, size_t ws_size,
                              hipStream_t stream) {
  const float* x  = (const float*)d_in[0];
  const float* Wq = (const float*)d_in[1];
  const float* Wk = (const float*)d_in[2];
  const float* Wv = (const float*)d_in[3];
  const float* Wo = (const float*)d_in[4];
  const float* bo = (const float*)d_in[5];
  float* out = (float*)d_out;

  const size_t NX = 8388608;   // B*S*D_MODEL
  const size_t NW = 1048576;   // per-projection weight elements
  const size_t NQ = 8388608;   // B*H*S*D_K

  char* p = (char*)d_ws;
  auto take = [&](size_t bytes) -> char* {
    char* r = p;
    p += (bytes + 255) & ~(size_t)255;
    return r;
  };
  short* xh  = (short*)take(NX * 2);
  short* xl  = (short*)take(NX * 2);
  short* Wh  = (short*)take(3 * NW * 2);
  short* Wl  = (short*)take(3 * NW * 2);
  short* Woh = (short*)take(NW * 2);
  short* Qh  = (short*)take(NQ * 2);
  short* Ql  = (short*)take(NQ * 2);
  short* Kh  = (short*)take(NQ * 2);
  short* Kl  = (short*)take(NQ * 2);
  short* Vt  = (short*)take(NQ * 2);
  short* Zb  = (short*)take(NQ * 2);

  split_pair<<<dim3((int)(NX / 256)), 256, 0, stream>>>(x, xh, xl, (int)NX);
  split_pair<<<dim3((int)(NW / 256)), 256, 0, stream>>>(Wq, Wh, Wl, (int)NW);
  split_pair<<<dim3((int)(NW / 256)), 256, 0, stream>>>(Wk, Wh + NW, Wl + NW, (int)NW);
  split_pair<<<dim3((int)(NW / 256)), 256, 0, stream>>>(Wv, Wh + 2 * NW, Wl + 2 * NW, (int)NW);
  cast_bf16<<<dim3((int)(NW / 256)), 256, 0, stream>>>(Wo, Woh, (int)NW);

  gemm_proj<<<dim3(24, 64), 256, 0, stream>>>(xh, xl, Wh, Wl, Qh, Ql, Kh, Kl, Vt);
  attn_kernel<<<dim3(2048), 256, 0, stream>>>(Qh, Ql, Kh, Kl, Vt, Zb);
  gemm_out<<<dim3(8, 64), 256, 0, stream>>>(Zb, Woh, bo, out);
}

// Round 6
// 414.894 us; speedup vs baseline: 1.2325x; 1.1156x over previous
//
#include <hip/hip_runtime.h>
#include <stdint.h>

// ---------- types ----------
typedef __attribute__((ext_vector_type(4))) float f32x4;
typedef __attribute__((ext_vector_type(8))) short short8;
typedef __attribute__((ext_vector_type(4))) unsigned int u32x4;
typedef __attribute__((ext_vector_type(2))) unsigned int u32x2;

#define MFMA_BF16(a, b, c) __builtin_amdgcn_mfma_f32_16x16x32_bf16(a, b, c, 0, 0, 0)

#define GLD16(gp, lp)                                                          \
  __builtin_amdgcn_global_load_lds(                                            \
      (const __attribute__((address_space(1))) void*)(gp),                     \
      (__attribute__((address_space(3))) void*)(lp), 16, 0, 0)

__device__ __forceinline__ short f2bf(float f) {
  union { float f; uint32_t u; } v; v.f = f;
  uint32_t r = (v.u + 0x7FFFu + ((v.u >> 16) & 1u)) >> 16;
  return (short)r;
}
__device__ __forceinline__ float bf2f(short s) {
  union { uint32_t u; float f; } v; v.u = ((uint32_t)(uint16_t)s) << 16;
  return v.f;
}
__device__ __forceinline__ float exp2_hw(float x) {
  float r;
  asm("v_exp_f32 %0, %1" : "=v"(r) : "v"(x));
  return r;
}
__device__ __forceinline__ uint32_t pkbf(float lo, float hi) {
  uint32_t r;
  asm("v_cvt_pk_bf16_f32 %0, %1, %2" : "=v"(r) : "v"(lo), "v"(hi));
  return r;
}

// ---------- elementwise split / cast ----------
__global__ __launch_bounds__(256) void split_pair(const float* __restrict__ src,
                                                  short* __restrict__ dh,
                                                  short* __restrict__ dl, int n) {
  int i = blockIdx.x * 256 + threadIdx.x;
  if (i < n) {
    float v = src[i];
    short hv = f2bf(v);
    dh[i] = hv;
    dl[i] = f2bf(v - bf2f(hv));
  }
}

__global__ __launch_bounds__(256) void cast_bf16(const float* __restrict__ src,
                                                 short* __restrict__ d, int n) {
  int i = blockIdx.x * 256 + threadIdx.x;
  if (i < n) d[i] = f2bf(src[i]);
}

// ---------- fused QKV projection GEMM ----------
// C[m,n] = sum_k X[m,k] * W[n,k],  M=8192, N=3072 (Q|K|V), K=1024
// 3-term split-bf16. Epilogue: Q/K -> hi/lo [B,H,S,64]; V -> TRANSPOSED [B,H,64,S].
__global__ __launch_bounds__(256) void gemm_proj(
    const short* __restrict__ Xh, const short* __restrict__ Xl,
    const short* __restrict__ Wh, const short* __restrict__ Wl,
    short* __restrict__ Qh, short* __restrict__ Ql,
    short* __restrict__ Kh, short* __restrict__ Kl,
    short* __restrict__ Vt) {
  __shared__ short sAh[128 * 32], sAl[128 * 32], sBh[128 * 32], sBl[128 * 32];
  const int tid = threadIdx.x, lane = tid & 63, w = tid >> 6;
  const int wr = w >> 1, wc = w & 1;
  const int g = lane >> 4, c = lane & 15;
  const int m0 = blockIdx.y * 128, n0 = blockIdx.x * 128;

  f32x4 acc[4][4];
#pragma unroll
  for (int i = 0; i < 4; i++)
#pragma unroll
    for (int j = 0; j < 4; j++) acc[i][j] = (f32x4){0.f, 0.f, 0.f, 0.f};

  for (int ks = 0; ks < 32; ks++) {
    const int k0 = ks * 32;
    __syncthreads();
#pragma unroll
    for (int i = 0; i < 2; i++) {
      const int chunk = i * 256 + w * 64 + lane;
      const int row = chunk >> 2;
      const int col = (chunk & 3) * 8;
      const size_t aoff = (size_t)(m0 + row) * 1024 + k0 + col;
      const size_t boff = (size_t)(n0 + row) * 1024 + k0 + col;
      const int ldsoff = (i * 256 + w * 64) * 16;
      GLD16(Xh + aoff, (char*)sAh + ldsoff);
      GLD16(Xl + aoff, (char*)sAl + ldsoff);
      GLD16(Wh + boff, (char*)sBh + ldsoff);
      GLD16(Wl + boff, (char*)sBl + ldsoff);
    }
    asm volatile("s_waitcnt vmcnt(0)" ::: "memory");
    __syncthreads();

    short8 ah[4], al[4], bh[4], bl[4];
#pragma unroll
    for (int i = 0; i < 4; i++) {
      const int ar = (wr * 64 + i * 16 + c) * 32 + g * 8;
      const int br = (wc * 64 + i * 16 + c) * 32 + g * 8;
      ah[i] = *(const short8*)&sAh[ar];
      al[i] = *(const short8*)&sAl[ar];
      bh[i] = *(const short8*)&sBh[br];
      bl[i] = *(const short8*)&sBl[br];
    }
#pragma unroll
    for (int i = 0; i < 4; i++)
#pragma unroll
      for (int j = 0; j < 4; j++) {
        acc[i][j] = MFMA_BF16(ah[i], bh[j], acc[i][j]);
        acc[i][j] = MFMA_BF16(ah[i], bl[j], acc[i][j]);
        acc[i][j] = MFMA_BF16(al[i], bh[j], acc[i][j]);
      }
  }

  const int section = n0 >> 10;  // 0=Q 1=K 2=V
#pragma unroll
  for (int i = 0; i < 4; i++)
#pragma unroll
    for (int j = 0; j < 4; j++)
#pragma unroll
      for (int r = 0; r < 4; r++) {
        const float v = acc[i][j][r];
        const int m = m0 + wr * 64 + i * 16 + g * 4 + r;
        const int n = n0 + wc * 64 + j * 16 + c;
        const int b = m >> 11, s = m & 2047;
        const int nn = n & 1023;
        const int hh = nn >> 6, d = nn & 63;
        if (section == 0) {
          const size_t off = ((size_t)(b * 16 + hh) * 2048 + s) * 64 + d;
          short hv = f2bf(v);
          Qh[off] = hv;
          Ql[off] = f2bf(v - bf2f(hv));
        } else if (section == 1) {
          const size_t off = ((size_t)(b * 16 + hh) * 2048 + s) * 64 + d;
          short hv = f2bf(v);
          Kh[off] = hv;
          Kl[off] = f2bf(v - bf2f(hv));
        } else {
          // transposed: Vt[(bh*64 + d)*2048 + s]
          Vt[((size_t)(b * 16 + hh) * 64 + d) * 2048 + s] = f2bf(v);
        }
      }
}

// ---------- flash attention ----------
// grid 2048 (XCD-chunked: 8 chunks of 256 = 8 bh x 32 qblk each).
// block = 256 (4 waves x 16 q-rows). KVBLK = 32, double-buffered 2-phase
// pipeline. SWAPPED-OPERAND scheme: QK^T computed as mfma(K, Q) so that
// D[k][q] has q = lane&15 -> each lane owns ONE q-row; softmax is almost
// entirely in-register (7 fmax + 2 shuffles), m/l state is scalar, P never
// touches LDS (cvt_pk + 8 shfl redistribution builds the PV B-fragment).
// PV computed as mfma(V, P) -> D[d][q]. K tile swizzle mask row&7; V tile
// (64B rows) mask (row>>1)&3. Softmax in exp2 domain, defer-max THR=8.
__global__ __launch_bounds__(256) void attn_kernel(
    const short* __restrict__ Qh, const short* __restrict__ Ql,
    const short* __restrict__ Kh, const short* __restrict__ Kl,
    const short* __restrict__ Vt, short* __restrict__ Z) {
  __shared__ short sKh[2][32 * 64], sKl[2][32 * 64];  // [k-row][d]
  __shared__ short sV[2][64 * 32];                    // [d-row][s]
  const int tid = threadIdx.x, lane = tid & 63, w = tid >> 6;
  const int g = lane >> 4, c = lane & 15;
  // XCD chunk swizzle: each XCD gets 256 consecutive work-ids (8 bh).
  const int L = blockIdx.x;
  const int wid = (L & 7) * 256 + (L >> 3);
  const int qblk = wid & 31, bh = wid >> 5;
  const int b = bh >> 4, h = bh & 15;
  const size_t base = (size_t)bh * (2048 * 64);

  // Q fragments (held for whole kernel); B-operand layout: lane holds
  // Q[q = c][d = cc*32 + g*8 + j]
  short8 qh[2], ql[2];
  {
    const int qrow = qblk * 64 + w * 16 + c;
#pragma unroll
    for (int cc = 0; cc < 2; cc++) {
      const size_t off = base + (size_t)qrow * 64 + cc * 32 + g * 8;
      qh[cc] = *(const short8*)(Qh + off);
      ql[cc] = *(const short8*)(Ql + off);
    }
  }

  f32x4 zacc[4];  // D[d][q]: zacc[dt][r] = Z[d = dt*16 + g*4 + r][q = c]
  float m_run = -INFINITY, l_part = 0.f;
#pragma unroll
  for (int dt = 0; dt < 4; dt++) zacc[dt] = (f32x4){0.f, 0.f, 0.f, 0.f};

  // fragment-read swizzled chunk offsets
  const int swK0 = ((0 * 4 + g) ^ (c & 7)) * 8;  // K d-chunks (8/row, 128B rows)
  const int swK1 = ((1 * 4 + g) ^ (c & 7)) * 8;
  const int swPV = (g ^ ((c >> 1) & 3)) * 8;     // V s-chunks (4/row, 64B rows)

  // staging geometry (256 threads, 1 chunk of 16B per array per thread)
  const int krow = tid >> 3, kcolg = (tid & 7) ^ (krow & 7);
  const int vrow = tid >> 2, vcolg = (tid & 3) ^ ((vrow >> 1) & 3);
  const int sldsoff = tid * 16;
  const size_t gK0 = base + (size_t)krow * 64 + kcolg * 8;    // + kt*2048
  const size_t gV0 = base + (size_t)vrow * 2048 + vcolg * 8;  // + kt*32

  auto stage = [&](int buf, int kt) {
    GLD16(Kh + gK0 + (size_t)kt * 2048, (char*)&sKh[buf][0] + sldsoff);
    GLD16(Kl + gK0 + (size_t)kt * 2048, (char*)&sKl[buf][0] + sldsoff);
    GLD16(Vt + gV0 + (size_t)kt * 32,   (char*)&sV[buf][0] + sldsoff);
  };

  const float CSCL = 11.5415603271f;  // 8 * log2(e): logits in exp2 domain
  const int srcl = ((g & 1) << 5) + c;  // shfl source lane for P redistribution

  auto compute = [&](int buf) {
    // QK^T swapped: D[k][q] = sum_d K[k][d] Q[q][d]; lane: q=c, k=t*16+g*4+r
    f32x4 sacc[2];
#pragma unroll
    for (int t = 0; t < 2; t++) sacc[t] = (f32x4){0.f, 0.f, 0.f, 0.f};
    __builtin_amdgcn_s_setprio(1);
#pragma unroll
    for (int cc = 0; cc < 2; cc++) {
      const int sw = cc ? swK1 : swK0;
#pragma unroll
      for (int t = 0; t < 2; t++) {
        const int kr = (t * 16 + c) * 64 + sw;
        short8 kh8 = *(const short8*)&sKh[buf][kr];
        short8 kl8 = *(const short8*)&sKl[buf][kr];
        sacc[t] = MFMA_BF16(kh8, qh[cc], sacc[t]);
        sacc[t] = MFMA_BF16(kh8, ql[cc], sacc[t]);
        sacc[t] = MFMA_BF16(kl8, qh[cc], sacc[t]);
      }
    }
    __builtin_amdgcn_s_setprio(0);

    // mask + log2-domain scale; p[t*4+r] = P-logit[k = t*16 + g*4 + r][q=c]
    float p[8];
#pragma unroll
    for (int t = 0; t < 2; t++)
#pragma unroll
      for (int r = 0; r < 4; r++) {
        const float s = sacc[t][r];
        p[t * 4 + r] = (s == 0.0f) ? -1e10f : s * CSCL;
      }
    // row max: 7 in-register + 2 shuffles (across g-lanes of same q)
    float mx = fmaxf(fmaxf(fmaxf(p[0], p[1]), fmaxf(p[2], p[3])),
                     fmaxf(fmaxf(p[4], p[5]), fmaxf(p[6], p[7])));
    mx = fmaxf(mx, __shfl_xor(mx, 16));
    mx = fmaxf(mx, __shfl_xor(mx, 32));
    // defer-max: rescale only when some row grew by > 8 (log2 units)
    if (__any(mx - m_run > 8.0f)) {
      const float mnew = fmaxf(m_run, mx);
      const float sc = exp2_hw(m_run - mnew);
      m_run = mnew;
      l_part *= sc;
#pragma unroll
      for (int dt = 0; dt < 4; dt++)
#pragma unroll
        for (int r = 0; r < 4; r++) zacc[dt][r] *= sc;
    }
#pragma unroll
    for (int i = 0; i < 8; i++) p[i] = exp2_hw(p[i] - m_run);
    l_part += ((p[0] + p[1]) + (p[2] + p[3])) + ((p[4] + p[5]) + (p[6] + p[7]));

    // pack P to bf16 pairs and redistribute into PV B-fragment:
    // B[k = g*8 + j][q = c]  <-  words from lanes (g&1)*32 + c and +16,
    // A-half (t=0) for g<2, B-half (t=1) for g>=2.
    const uint32_t wA0 = pkbf(p[0], p[1]), wA1 = pkbf(p[2], p[3]);
    const uint32_t wB0 = pkbf(p[4], p[5]), wB1 = pkbf(p[6], p[7]);
    const uint32_t a0 = __shfl(wA0, srcl), a1 = __shfl(wA1, srcl);
    const uint32_t b0 = __shfl(wB0, srcl), b1 = __shfl(wB1, srcl);
    const uint32_t a2 = __shfl(wA0, srcl + 16), a3 = __shfl(wA1, srcl + 16);
    const uint32_t b2 = __shfl(wB0, srcl + 16), b3 = __shfl(wB1, srcl + 16);
    union { u32x4 u; short8 s; } pf;
    pf.u[0] = (g < 2) ? a0 : b0;
    pf.u[1] = (g < 2) ? a1 : b1;
    pf.u[2] = (g < 2) ? a2 : b2;
    pf.u[3] = (g < 2) ? a3 : b3;

    // PV swapped: D[d][q] = sum_k V[k][d] P[k][q] = mfma(Vt-frag, P-frag)
    __builtin_amdgcn_s_setprio(1);
#pragma unroll
    for (int dt = 0; dt < 4; dt++) {
      short8 vb = *(const short8*)&sV[buf][(dt * 16 + c) * 32 + swPV];
      zacc[dt] = MFMA_BF16(vb, pf.s, zacc[dt]);
    }
    __builtin_amdgcn_s_setprio(0);
  };

  // prologue
  stage(0, 0);
  asm volatile("s_waitcnt vmcnt(0)" ::: "memory");
  __builtin_amdgcn_s_barrier();

#pragma unroll 1
  for (int t2 = 0; t2 < 32; t2++) {
    {
      stage(1, 2 * t2 + 1);     // prefetch next tile into buf1
      compute(0);               // compute current from buf0
      asm volatile("s_waitcnt vmcnt(0) lgkmcnt(0)" ::: "memory");
      __builtin_amdgcn_s_barrier();
    }
    {
      const int nxt = 2 * t2 + 2;
      stage(0, nxt < 64 ? nxt : 63);  // clamp (last restages 63, unused)
      compute(1);
      asm volatile("s_waitcnt vmcnt(0) lgkmcnt(0)" ::: "memory");
      __builtin_amdgcn_s_barrier();
    }
  }

  // epilogue: reduce row sum across the 4 g-lanes, normalize, store Z bf16
  float rs = l_part;
  rs += __shfl_xor(rs, 16);
  rs += __shfl_xor(rs, 32);
  const float inv = rs > 0.f ? 1.0f / rs : 0.f;
  const int qg = qblk * 64 + w * 16 + c;
#pragma unroll
  for (int dt = 0; dt < 4; dt++) {
    u32x2 zw;
    zw[0] = pkbf(zacc[dt][0] * inv, zacc[dt][1] * inv);
    zw[1] = pkbf(zacc[dt][2] * inv, zacc[dt][3] * inv);
    *reinterpret_cast<u32x2*>(
        &Z[(size_t)(b * 2048 + qg) * 1024 + h * 64 + dt * 16 + g * 4]) = zw;
  }
}

// ---------- output projection GEMM ----------
// out[m,n] = sum_k Z[m,k]*Wo[n,k] + bo[n], M=8192, N=1024, K=1024, fp32 out
__global__ __launch_bounds__(256) void gemm_out(
    const short* __restrict__ Zb, const short* __restrict__ Wob,
    const float* __restrict__ bo, float* __restrict__ out) {
  __shared__ short sA[128 * 32], sB[128 * 32];
  const int tid = threadIdx.x, lane = tid & 63, w = tid >> 6;
  const int wr = w >> 1, wc = w & 1;
  const int g = lane >> 4, c = lane & 15;
  const int m0 = blockIdx.y * 128, n0 = blockIdx.x * 128;

  f32x4 acc[4][4];
#pragma unroll
  for (int i = 0; i < 4; i++)
#pragma unroll
    for (int j = 0; j < 4; j++) acc[i][j] = (f32x4){0.f, 0.f, 0.f, 0.f};

  for (int ks = 0; ks < 32; ks++) {
    const int k0 = ks * 32;
    __syncthreads();
#pragma unroll
    for (int i = 0; i < 2; i++) {
      const int chunk = i * 256 + w * 64 + lane;
      const int row = chunk >> 2;
      const int col = (chunk & 3) * 8;
      const size_t aoff = (size_t)(m0 + row) * 1024 + k0 + col;
      const size_t boff = (size_t)(n0 + row) * 1024 + k0 + col;
      const int ldsoff = (i * 256 + w * 64) * 16;
      GLD16(Zb + aoff, (char*)sA + ldsoff);
      GLD16(Wob + boff, (char*)sB + ldsoff);
    }
    asm volatile("s_waitcnt vmcnt(0)" ::: "memory");
    __syncthreads();

    short8 a[4], b8[4];
#pragma unroll
    for (int i = 0; i < 4; i++) {
      a[i] = *(const short8*)&sA[(wr * 64 + i * 16 + c) * 32 + g * 8];
      b8[i] = *(const short8*)&sB[(wc * 64 + i * 16 + c) * 32 + g * 8];
    }
#pragma unroll
    for (int i = 0; i < 4; i++)
#pragma unroll
      for (int j = 0; j < 4; j++) acc[i][j] = MFMA_BF16(a[i], b8[j], acc[i][j]);
  }

#pragma unroll
  for (int i = 0; i < 4; i++)
#pragma unroll
    for (int j = 0; j < 4; j++)
#pragma unroll
      for (int r = 0; r < 4; r++) {
        const int m = m0 + wr * 64 + i * 16 + g * 4 + r;
        const int n = n0 + wc * 64 + j * 16 + c;
        out[(size_t)m * 1024 + n] = acc[i][j][r] + bo[n];
      }
}

// ---------- host ----------
extern "C" void kernel_launch(void* const* d_in, const int* in_sizes, int n_in,
                              void* d_out, int out_size, void* d_ws, size_t ws_size,
                              hipStream_t stream) {
  const float* x  = (const float*)d_in[0];
  const float* Wq = (const float*)d_in[1];
  const float* Wk = (const float*)d_in[2];
  const float* Wv = (const float*)d_in[3];
  const float* Wo = (const float*)d_in[4];
  const float* bo = (const float*)d_in[5];
  float* out = (float*)d_out;

  const size_t NX = 8388608;   // B*S*D_MODEL
  const size_t NW = 1048576;   // per-projection weight elements
  const size_t NQ = 8388608;   // B*H*S*D_K

  char* p = (char*)d_ws;
  auto take = [&](size_t bytes) -> char* {
    char* r = p;
    p += (bytes + 255) & ~(size_t)255;
    return r;
  };
  short* xh  = (short*)take(NX * 2);
  short* xl  = (short*)take(NX * 2);
  short* Wh  = (short*)take(3 * NW * 2);
  short* Wl  = (short*)take(3 * NW * 2);
  short* Woh = (short*)take(NW * 2);
  short* Qh  = (short*)take(NQ * 2);
  short* Ql  = (short*)take(NQ * 2);
  short* Kh  = (short*)take(NQ * 2);
  short* Kl  = (short*)take(NQ * 2);
  short* Vt  = (short*)take(NQ * 2);
  short* Zb  = (short*)take(NQ * 2);

  split_pair<<<dim3((int)(NX / 256)), 256, 0, stream>>>(x, xh, xl, (int)NX);
  split_pair<<<dim3((int)(NW / 256)), 256, 0, stream>>>(Wq, Wh, Wl, (int)NW);
  split_pair<<<dim3((int)(NW / 256)), 256, 0, stream>>>(Wk, Wh + NW, Wl + NW, (int)NW);
  split_pair<<<dim3((int)(NW / 256)), 256, 0, stream>>>(Wv, Wh + 2 * NW, Wl + 2 * NW, (int)NW);
  cast_bf16<<<dim3((int)(NW / 256)), 256, 0, stream>>>(Wo, Woh, (int)NW);

  gemm_proj<<<dim3(24, 64), 256, 0, stream>>>(xh, xl, Wh, Wl, Qh, Ql, Kh, Kl, Vt);
  attn_kernel<<<dim3(2048), 256, 0, stream>>>(Qh, Ql, Kh, Kl, Vt, Zb);
  gemm_out<<<dim3(8, 64), 256, 0, stream>>>(Zb, Woh, bo, out);
}